// Round 4
// baseline (670.405 us; speedup 1.0000x reference)
//
#include <hip/hip_runtime.h>
#include <hip/hip_bf16.h>
#include <cstdint>

// B=4, S=1024, E=1024, H=16, D=64.
// d_out = [ out (4M floats) | filtered_attn (64M floats) ].
// Pipeline: split_f32 -> gemm<0> (QKV proj, split-bf16; Q pre-scaled by 1/8)
// -> fused_attn (QK^T + softmax/filter + PV; logits register-resident;
//    QBLK=32: two 16-row strips share K/V reads) -> gemm<3> (out proj).

#define BB 4
#define SS 1024
#define EE 1024
#define HH 16
#define DD 64

typedef __attribute__((ext_vector_type(8))) short bf16x8;
typedef __attribute__((ext_vector_type(4))) float f32x4;

// ---------------------------------------------------------------------------
// split cast: hi = bf16(v), lo = bf16(v - hi). lo may be null (plain cast).
// ---------------------------------------------------------------------------
__global__ __launch_bounds__(256) void split_f32(
    const float* __restrict__ in, __hip_bfloat16* __restrict__ hi,
    __hip_bfloat16* __restrict__ lo, int n4) {
  int i = blockIdx.x * 256 + threadIdx.x;
  if (i >= n4) return;
  float4 v = ((const float4*)in)[i];
  float vv[4] = {v.x, v.y, v.z, v.w};
  __hip_bfloat16 h[4], l[4];
#pragma unroll
  for (int j = 0; j < 4; ++j) {
    h[j] = __float2bfloat16(vv[j]);
    l[j] = __float2bfloat16(vv[j] - __bfloat162float(h[j]));
  }
  ((ushort4*)hi)[i] = *(ushort4*)h;
  if (lo) ((ushort4*)lo)[i] = *(ushort4*)l;
}

// ---------------------------------------------------------------------------
// NT GEMM: C[m][n] = sum_k A[m*lda+k]*B[n*ldb+k]. 128x128 tile, BK=64,
// 4 waves (2x2), 4x4 x 16x16x32 bf16 MFMA per wave.
// MODE 0 (SPLIT): A=(xh,xl) B=(Wqh,Wql); +bias(f32); out: qh,ql,kh,kl
//   [B,H,S,D] (Q pre-scaled by 0.125 — exact pow2, commutes with split),
//   vT [B,H,D,S].
// MODE 3: A=ao B=Wproj_h; +bias(f32); out fp32 oF[m*E+n]
// ---------------------------------------------------------------------------
template <int MODE>
__global__ __launch_bounds__(256) void gemm(
    const __hip_bfloat16* __restrict__ Ah, const __hip_bfloat16* __restrict__ Al,
    const __hip_bfloat16* __restrict__ Bh, const __hip_bfloat16* __restrict__ Bl,
    const float* __restrict__ Af, const float* __restrict__ bias,
    float* __restrict__ oF, __hip_bfloat16* __restrict__ o1,
    __hip_bfloat16* __restrict__ o2, __hip_bfloat16* __restrict__ o3,
    __hip_bfloat16* __restrict__ o4, __hip_bfloat16* __restrict__ o5,
    int M, int N, int K, int lda, int ldb, long long sA, long long sB) {
  constexpr bool SPLIT = (MODE == 0 || MODE == 1);
  constexpr bool AF32  = (MODE == 2);

  const int tid  = threadIdx.x;
  const int lane = tid & 63;
  const int wave = tid >> 6;
  const int wm   = (wave >> 1) * 64;
  const int wn   = (wave & 1) * 64;
  const int quad = lane >> 4;
  const int l15  = lane & 15;
  const int m0   = blockIdx.y * 128;
  const int n0   = blockIdx.x * 128;
  const long long zz = blockIdx.z;

  if (AF32) Af += zz * sA;
  else { Ah += zz * sA; if (SPLIT) Al += zz * sA; }
  Bh += zz * sB;
  if (SPLIT) Bl += zz * sB;

  __shared__ __align__(16) __hip_bfloat16 lds[(SPLIT ? 4 : 2) * 128 * 72];
  __hip_bfloat16* lAh = lds;
  __hip_bfloat16* lAl = SPLIT ? lds + 128 * 72 : nullptr;
  __hip_bfloat16* lBh = lds + (SPLIT ? 2 : 1) * 128 * 72;
  __hip_bfloat16* lBl = SPLIT ? lds + 3 * 128 * 72 : nullptr;

  f32x4 acc[4][4] = {};

  for (int k0 = 0; k0 < K; k0 += 64) {
#pragma unroll
    for (int it = 0; it < 4; ++it) {
      int flat = (it * 256 + tid) * 8;
      int row  = flat >> 6;
      int kk   = flat & 63;
      const bool mok = (m0 + row < M);
      const bool nok = (n0 + row < N);
      if (AF32) {
        float4 f0 = {0, 0, 0, 0}, f1 = {0, 0, 0, 0};
        if (mok) {
          const float* src = Af + (long long)(m0 + row) * lda + k0 + kk;
          f0 = *(const float4*)src;
          f1 = *(const float4*)(src + 4);
        }
        __hip_bfloat16 t[8];
        t[0] = __float2bfloat16(f0.x); t[1] = __float2bfloat16(f0.y);
        t[2] = __float2bfloat16(f0.z); t[3] = __float2bfloat16(f0.w);
        t[4] = __float2bfloat16(f1.x); t[5] = __float2bfloat16(f1.y);
        t[6] = __float2bfloat16(f1.z); t[7] = __float2bfloat16(f1.w);
        *(uint4*)&lAh[row * 72 + kk] = *(uint4*)t;
      } else {
        uint4 va = {0, 0, 0, 0};
        if (mok) va = *(const uint4*)(Ah + (long long)(m0 + row) * lda + k0 + kk);
        *(uint4*)&lAh[row * 72 + kk] = va;
        if (SPLIT) {
          uint4 vl = {0, 0, 0, 0};
          if (mok) vl = *(const uint4*)(Al + (long long)(m0 + row) * lda + k0 + kk);
          *(uint4*)&lAl[row * 72 + kk] = vl;
        }
      }
      uint4 vb = {0, 0, 0, 0};
      if (nok) vb = *(const uint4*)(Bh + (long long)(n0 + row) * ldb + k0 + kk);
      *(uint4*)&lBh[row * 72 + kk] = vb;
      if (SPLIT) {
        uint4 vbl = {0, 0, 0, 0};
        if (nok) vbl = *(const uint4*)(Bl + (long long)(n0 + row) * ldb + k0 + kk);
        *(uint4*)&lBl[row * 72 + kk] = vbl;
      }
    }
    __syncthreads();

#pragma unroll
    for (int ks = 0; ks < 64; ks += 32) {
      bf16x8 ah[4], bh[4], al[4], bl[4];
#pragma unroll
      for (int i = 0; i < 4; ++i) {
        int off = (wm + i * 16 + l15) * 72 + ks + quad * 8;
        ah[i] = *(const bf16x8*)&lAh[off];
        if (SPLIT) al[i] = *(const bf16x8*)&lAl[off];
      }
#pragma unroll
      for (int j = 0; j < 4; ++j) {
        int off = (wn + j * 16 + l15) * 72 + ks + quad * 8;
        bh[j] = *(const bf16x8*)&lBh[off];
        if (SPLIT) bl[j] = *(const bf16x8*)&lBl[off];
      }
#pragma unroll
      for (int i = 0; i < 4; ++i)
#pragma unroll
        for (int j = 0; j < 4; ++j) {
          if (SPLIT) {
            acc[i][j] = __builtin_amdgcn_mfma_f32_16x16x32_bf16(al[i], bh[j], acc[i][j], 0, 0, 0);
            acc[i][j] = __builtin_amdgcn_mfma_f32_16x16x32_bf16(ah[i], bl[j], acc[i][j], 0, 0, 0);
          }
          acc[i][j] = __builtin_amdgcn_mfma_f32_16x16x32_bf16(ah[i], bh[j], acc[i][j], 0, 0, 0);
        }
    }
    __syncthreads();
  }

  // C/D layout: col = lane&15, row = quad*4 + reg
#pragma unroll
  for (int i = 0; i < 4; ++i) {
#pragma unroll
    for (int j = 0; j < 4; ++j) {
#pragma unroll
      for (int r = 0; r < 4; ++r) {
        int m = m0 + wm + i * 16 + quad * 4 + r;
        int n = n0 + wn + j * 16 + l15;
        float v = acc[i][j][r];
        if (MODE == 0) {
          v += bias[n];
          int c = n >> 10, nn = n & 1023, h = nn >> 6, d = nn & 63;
          int b = m >> 10, s = m & 1023;
          long long idx = (((long long)(b * HH + h) * SS + s) << 6) + d;
          if (c == 0) {
            v *= 0.125f;  // fold D^-0.5 into Q (exact pow2)
            __hip_bfloat16 hh = __float2bfloat16(v);
            o1[idx] = hh;
            o2[idx] = __float2bfloat16(v - __bfloat162float(hh));
          } else if (c == 1) {
            __hip_bfloat16 hh = __float2bfloat16(v);
            o3[idx] = hh;
            o4[idx] = __float2bfloat16(v - __bfloat162float(hh));
          } else {
            o5[(((long long)(b * HH + h) * DD + d) << 10) + s] = __float2bfloat16(v);
          }
        } else if (MODE == 1) {
          oF[zz * (SS * SS) + (long long)m * SS + n] = v * 0.125f;
        } else if (MODE == 2) {
          if (n < DD) {
            int b = (int)(zz >> 4), h = (int)(zz & 15);
            o1[(((long long)(b * SS + m)) << 10) + h * DD + n] = __float2bfloat16(v);
          }
        } else {
          oF[(long long)m * EE + n] = v + bias[n];
        }
      }
    }
  }
}

// ---------------------------------------------------------------------------
// 16-lane-group reductions (lanes quad*16 .. quad*16+15; xor<=8 stays in group)
// ---------------------------------------------------------------------------
__device__ __forceinline__ float qg_max16(float v) {
#pragma unroll
  for (int o = 8; o > 0; o >>= 1) v = fmaxf(v, __shfl_xor(v, o));
  return v;
}
__device__ __forceinline__ float qg_sum16(float v) {
#pragma unroll
  for (int o = 8; o > 0; o >>= 1) v += __shfl_xor(v, o);
  return v;
}

// ---------------------------------------------------------------------------
// fused_attn v4: one block per (bh, 32-row Q tile = two 16-row strips).
// 8 waves / 512 threads.
// Phase 1: wave w owns k-cols [w*128,+128) for BOTH strips -> acc0[8],acc1[8]
//   f32x4 (64 VGPR). K frags are loaded ONCE and feed 6 MFMAs (3 per strip):
//   2x MFMA density, half the cache-read traffic of v3 (K read once per
//   32 rows instead of per 16).
// Softmax: per strip: lane-tree over nt -> l15-group shfl -> cross-wave LDS
//   combine red[3][8][32]. Division-free filter. Q pre-scaled in gemm<0>.
// P: f32 normal stores -> global attn (NT reverted: it amplified WRITE_SIZE
//   353 vs 290 MB), bf16 -> Pl[32][1032].
// Phase 3: wave w -> d-group (w&3)*16, k-half (w>>2)*512, both strips; V read
//   exactly once per block. Partial O via Obuf[4][32][17]; waves 0-3 finalize.
// LDS 77.8 KB; __launch_bounds__(512,4) caps VGPR at 128 -> 2 blocks/CU.
// ---------------------------------------------------------------------------
__global__ __launch_bounds__(512, 4) void fused_attn(
    const __hip_bfloat16* __restrict__ qh, const __hip_bfloat16* __restrict__ ql,
    const __hip_bfloat16* __restrict__ kh, const __hip_bfloat16* __restrict__ kl,
    const __hip_bfloat16* __restrict__ vT, float* __restrict__ attn,
    __hip_bfloat16* __restrict__ ao) {
  const int tid  = threadIdx.x;
  const int lane = tid & 63;
  const int wave = tid >> 6;   // 0..7
  const int quad = lane >> 4;
  const int l15  = lane & 15;

  // XCD-chunked swizzle (gridDim.x is a multiple of 8 -> bijective)
  int id = blockIdx.x;
  const int q8 = gridDim.x >> 3;
  id = (id & 7) * q8 + (id >> 3);
  const int bh = id >> 5;          // 32 Q-tiles per bh
  const int q0 = (id & 31) * 32;

  const int brow = (bh >> 4) * SS;   // 0 in per-batch mode (bh = h < 16)
  const int h    = bh & 15;
  const long long qbase = ((long long)bh * SS + q0) * DD;
  const long long kbase = (long long)bh * SS * DD;
  const long long vbase = (long long)bh * DD * SS;
  const long long abase = ((long long)bh * SS + q0) * SS;

  __shared__ __align__(16) __hip_bfloat16 Pl[32][1032];  // 66,048 B
  __shared__ float red[3][8][32];                        //  3,072 B
  __shared__ float Obuf[4][32][17];                      //  8,704 B

  // --- Q A-frags for both strips (row l15 + s*16, k-cols quad*8, +32) ---
  bf16x8 aqh0[2], aqh1[2], aql0[2], aql1[2];   // [strip]
#pragma unroll
  for (int s = 0; s < 2; ++s) {
    const __hip_bfloat16* ph = qh + qbase + (s * 16 + l15) * DD + quad * 8;
    const __hip_bfloat16* pl = ql + qbase + (s * 16 + l15) * DD + quad * 8;
    aqh0[s] = *(const bf16x8*)(ph);
    aqh1[s] = *(const bf16x8*)(ph + 32);
    aql0[s] = *(const bf16x8*)(pl);
    aql1[s] = *(const bf16x8*)(pl + 32);
  }

  // --- Phase 1: QK^T, register-resident; wave owns k in [wave*128,+128) ---
  f32x4 acc0[8], acc1[8];
  const __hip_bfloat16* pkh0 = kh + kbase + (long long)(wave * 128 + l15) * DD + quad * 8;
  const __hip_bfloat16* pkl0 = kl + kbase + (long long)(wave * 128 + l15) * DD + quad * 8;
#pragma unroll
  for (int nt = 0; nt < 8; ++nt) {
    const __hip_bfloat16* pkh = pkh0 + nt * 16 * DD;
    const __hip_bfloat16* pkl = pkl0 + nt * 16 * DD;
    f32x4 a0 = {}, a1 = {};
    {  // kc = 0 (k 0..31 of D)
      bf16x8 b = *(const bf16x8*)(pkh);
      bf16x8 c = *(const bf16x8*)(pkl);
      __builtin_amdgcn_s_setprio(1);
      a0 = __builtin_amdgcn_mfma_f32_16x16x32_bf16(aql0[0], b, a0, 0, 0, 0);
      a1 = __builtin_amdgcn_mfma_f32_16x16x32_bf16(aql0[1], b, a1, 0, 0, 0);
      a0 = __builtin_amdgcn_mfma_f32_16x16x32_bf16(aqh0[0], c, a0, 0, 0, 0);
      a1 = __builtin_amdgcn_mfma_f32_16x16x32_bf16(aqh0[1], c, a1, 0, 0, 0);
      a0 = __builtin_amdgcn_mfma_f32_16x16x32_bf16(aqh0[0], b, a0, 0, 0, 0);
      a1 = __builtin_amdgcn_mfma_f32_16x16x32_bf16(aqh0[1], b, a1, 0, 0, 0);
      __builtin_amdgcn_s_setprio(0);
    }
    {  // kc = 1 (k 32..63 of D)
      bf16x8 b = *(const bf16x8*)(pkh + 32);
      bf16x8 c = *(const bf16x8*)(pkl + 32);
      __builtin_amdgcn_s_setprio(1);
      a0 = __builtin_amdgcn_mfma_f32_16x16x32_bf16(aql1[0], b, a0, 0, 0, 0);
      a1 = __builtin_amdgcn_mfma_f32_16x16x32_bf16(aql1[1], b, a1, 0, 0, 0);
      a0 = __builtin_amdgcn_mfma_f32_16x16x32_bf16(aqh1[0], c, a0, 0, 0, 0);
      a1 = __builtin_amdgcn_mfma_f32_16x16x32_bf16(aqh1[1], c, a1, 0, 0, 0);
      a0 = __builtin_amdgcn_mfma_f32_16x16x32_bf16(aqh1[0], b, a0, 0, 0, 0);
      a1 = __builtin_amdgcn_mfma_f32_16x16x32_bf16(aqh1[1], b, a1, 0, 0, 0);
      __builtin_amdgcn_s_setprio(0);
    }
    acc0[nt] = a0;
    acc1[nt] = a1;
  }
  // (Q was pre-scaled by 0.125 in gemm<0>; logits already scaled.)

  // --- row max per strip: lane tree over nt -> l15-group -> cross-wave ---
  {
    float mx0[4], mx1[4];
#pragma unroll
    for (int r = 0; r < 4; ++r) {
      float a = fmaxf(fmaxf(fmaxf(acc0[0][r], acc0[1][r]), fmaxf(acc0[2][r], acc0[3][r])),
                      fmaxf(fmaxf(acc0[4][r], acc0[5][r]), fmaxf(acc0[6][r], acc0[7][r])));
      mx0[r] = qg_max16(a);
      float b = fmaxf(fmaxf(fmaxf(acc1[0][r], acc1[1][r]), fmaxf(acc1[2][r], acc1[3][r])),
                      fmaxf(fmaxf(acc1[4][r], acc1[5][r]), fmaxf(acc1[6][r], acc1[7][r])));
      mx1[r] = qg_max16(b);
    }
    if (l15 == 0) {
#pragma unroll
      for (int r = 0; r < 4; ++r) {
        red[0][wave][quad * 4 + r]      = mx0[r];
        red[0][wave][16 + quad * 4 + r] = mx1[r];
      }
    }
  }
  __syncthreads();
  float m0[4], m1[4];
#pragma unroll
  for (int r = 0; r < 4; ++r) {
    const int q = quad * 4 + r;
    m0[r] = fmaxf(fmaxf(fmaxf(red[0][0][q], red[0][1][q]), fmaxf(red[0][2][q], red[0][3][q])),
                  fmaxf(fmaxf(red[0][4][q], red[0][5][q]), fmaxf(red[0][6][q], red[0][7][q])));
    m1[r] = fmaxf(fmaxf(fmaxf(red[0][0][16 + q], red[0][1][16 + q]), fmaxf(red[0][2][16 + q], red[0][3][16 + q])),
                  fmaxf(fmaxf(red[0][4][16 + q], red[0][5][16 + q]), fmaxf(red[0][6][16 + q], red[0][7][16 + q])));
  }

  // --- e = exp(v - m), Z ---
  {
    float z0[4] = {0.f, 0.f, 0.f, 0.f}, z1[4] = {0.f, 0.f, 0.f, 0.f};
#pragma unroll
    for (int nt = 0; nt < 8; ++nt)
#pragma unroll
      for (int r = 0; r < 4; ++r) {
        float e0 = expf(acc0[nt][r] - m0[r]);
        acc0[nt][r] = e0; z0[r] += e0;
        float e1 = expf(acc1[nt][r] - m1[r]);
        acc1[nt][r] = e1; z1[r] += e1;
      }
#pragma unroll
    for (int r = 0; r < 4; ++r) { z0[r] = qg_sum16(z0[r]); z1[r] = qg_sum16(z1[r]); }
    if (l15 == 0) {
#pragma unroll
      for (int r = 0; r < 4; ++r) {
        red[1][wave][quad * 4 + r]      = z0[r];
        red[1][wave][16 + quad * 4 + r] = z1[r];
      }
    }
  }
  __syncthreads();
  float c0[4], c1[4];
#pragma unroll
  for (int r = 0; r < 4; ++r) {
    const int q = quad * 4 + r;
    const float Z0 = ((red[1][0][q] + red[1][1][q]) + (red[1][2][q] + red[1][3][q])) +
                     ((red[1][4][q] + red[1][5][q]) + (red[1][6][q] + red[1][7][q]));
    const float Z1 = ((red[1][0][16 + q] + red[1][1][16 + q]) + (red[1][2][16 + q] + red[1][3][16 + q])) +
                     ((red[1][4][16 + q] + red[1][5][16 + q]) + (red[1][6][16 + q] + red[1][7][16 + q]));
    c0[r] = 4e-4f * Z0;   // sel: e > c  <=>  e/Z > 4e-4
    c1[r] = 4e-4f * Z1;
  }

  // --- Zs = sum of selected e ---
  {
    float s0[4] = {0.f, 0.f, 0.f, 0.f}, s1[4] = {0.f, 0.f, 0.f, 0.f};
#pragma unroll
    for (int nt = 0; nt < 8; ++nt)
#pragma unroll
      for (int r = 0; r < 4; ++r) {
        if (acc0[nt][r] > c0[r]) s0[r] += acc0[nt][r];
        if (acc1[nt][r] > c1[r]) s1[r] += acc1[nt][r];
      }
#pragma unroll
    for (int r = 0; r < 4; ++r) { s0[r] = qg_sum16(s0[r]); s1[r] = qg_sum16(s1[r]); }
    if (l15 == 0) {
#pragma unroll
      for (int r = 0; r < 4; ++r) {
        red[2][wave][quad * 4 + r]      = s0[r];
        red[2][wave][16 + quad * 4 + r] = s1[r];
      }
    }
  }
  __syncthreads();
  float rinv0[4], rinv1[4];
#pragma unroll
  for (int r = 0; r < 4; ++r) {
    const int q = quad * 4 + r;
    const float Zs0 = ((red[2][0][q] + red[2][1][q]) + (red[2][2][q] + red[2][3][q])) +
                      ((red[2][4][q] + red[2][5][q]) + (red[2][6][q] + red[2][7][q]));
    const float Zs1 = ((red[2][0][16 + q] + red[2][1][16 + q]) + (red[2][2][16 + q] + red[2][3][16 + q])) +
                      ((red[2][4][16 + q] + red[2][5][16 + q]) + (red[2][6][16 + q] + red[2][7][16 + q]));
    rinv0[r] = 1.0f / Zs0;   // row max always selected -> Zs >= 1
    rinv1[r] = 1.0f / Zs1;
  }

  // --- write filtered probs: f32 -> global (required), bf16 -> LDS (P) ---
#pragma unroll
  for (int nt = 0; nt < 8; ++nt) {
    const int k = wave * 128 + nt * 16 + l15;
#pragma unroll
    for (int r = 0; r < 4; ++r) {
      const int q = quad * 4 + r;
      const float e0 = acc0[nt][r];
      const float p0 = (e0 > c0[r]) ? e0 * rinv0[r] : 0.f;
      attn[abase + (long long)q * SS + k] = p0;
      Pl[q][k] = __float2bfloat16(p0);
      const float e1 = acc1[nt][r];
      const float p1 = (e1 > c1[r]) ? e1 * rinv1[r] : 0.f;
      attn[abase + (long long)(16 + q) * SS + k] = p1;
      Pl[16 + q][k] = __float2bfloat16(p1);
    }
  }
  __syncthreads();

  // --- Phase 3: PV. wave -> d-group (w&3)*16, k-half (w>>2)*512, 2 strips ---
  const int d0  = (wave & 3) * 16;
  const int kh2 = (wave >> 2) * 512;
  f32x4 oA0 = {}, oA1 = {}, oB0 = {}, oB1 = {};
  const __hip_bfloat16* pv  = vT + vbase + (long long)(d0 + l15) * SS + kh2 + quad * 8;
  const __hip_bfloat16* pp0 = &Pl[l15][kh2] + quad * 8;
  const __hip_bfloat16* pp1 = &Pl[16 + l15][kh2] + quad * 8;
#pragma unroll
  for (int ks = 0; ks < 16; ks += 2) {
    bf16x8 v0  = *(const bf16x8*)(pv + ks * 32);
    bf16x8 v1  = *(const bf16x8*)(pv + (ks + 1) * 32);
    bf16x8 a00 = *(const bf16x8*)(pp0 + ks * 32);
    bf16x8 a01 = *(const bf16x8*)(pp0 + (ks + 1) * 32);
    bf16x8 a10 = *(const bf16x8*)(pp1 + ks * 32);
    bf16x8 a11 = *(const bf16x8*)(pp1 + (ks + 1) * 32);
    __builtin_amdgcn_s_setprio(1);
    oA0 = __builtin_amdgcn_mfma_f32_16x16x32_bf16(a00, v0, oA0, 0, 0, 0);
    oB0 = __builtin_amdgcn_mfma_f32_16x16x32_bf16(a10, v0, oB0, 0, 0, 0);
    oA1 = __builtin_amdgcn_mfma_f32_16x16x32_bf16(a01, v1, oA1, 0, 0, 0);
    oB1 = __builtin_amdgcn_mfma_f32_16x16x32_bf16(a11, v1, oB1, 0, 0, 0);
    __builtin_amdgcn_s_setprio(0);
  }
  float oS0[4], oS1[4];
#pragma unroll
  for (int r = 0; r < 4; ++r) { oS0[r] = oA0[r] + oA1[r]; oS1[r] = oB0[r] + oB1[r]; }

  if (wave >= 4) {
#pragma unroll
    for (int r = 0; r < 4; ++r) {
      Obuf[wave & 3][quad * 4 + r][l15]      = oS0[r];
      Obuf[wave & 3][16 + quad * 4 + r][l15] = oS1[r];
    }
  }
  __syncthreads();
  if (wave < 4) {
    // C: row(q) = quad*4+r, col(d) = l15
#pragma unroll
    for (int r = 0; r < 4; ++r) {
      const int qA = q0 + quad * 4 + r;
      const int qB = qA + 16;
      const float vA = oS0[r] + Obuf[wave][quad * 4 + r][l15];
      const float vB = oS1[r] + Obuf[wave][16 + quad * 4 + r][l15];
      ao[((long long)(brow + qA)) * EE + h * DD + d0 + l15] = __float2bfloat16(vA);
      ao[((long long)(brow + qB)) * EE + h * DD + d0 + l15] = __float2bfloat16(vB);
    }
  }
}

// ---------------------------------------------------------------------------
extern "C" void kernel_launch(void* const* d_in, const int* in_sizes, int n_in,
                              void* d_out, int out_size, void* d_ws, size_t ws_size,
                              hipStream_t stream) {
  const float* x     = (const float*)d_in[0];  // [4,1024,1024]
  const float* Wqkv  = (const float*)d_in[1];  // [3072,1024]
  const float* bqkv  = (const float*)d_in[2];  // [3072]
  const float* Wproj = (const float*)d_in[3];  // [1024,1024]
  const float* bproj = (const float*)d_in[4];  // [1024]

  float* out   = (float*)d_out;                        // 4M floats
  float* attnF = out + (size_t)BB * SS * EE;           // 64M floats

  const size_t M1 = 1024 * 1024;
  __hip_bfloat16* w = (__hip_bfloat16*)d_ws;

  if (ws_size >= (size_t)80 * 1024 * 1024) {
    // flat: 39M bf16 elems = 78MB
    __hip_bfloat16 *xh = w, *xl = xh + 4 * M1;
    __hip_bfloat16 *Wqh = xl + 4 * M1, *Wql = Wqh + 3 * M1, *Wph = Wql + 3 * M1;
    __hip_bfloat16 *qh = Wph + M1, *ql = qh + 4 * M1, *kh = ql + 4 * M1, *kl = kh + 4 * M1;
    __hip_bfloat16 *vT = kl + 4 * M1, *ao = vT + 4 * M1;

    split_f32<<<4096, 256, 0, stream>>>(x, xh, xl, 1024 * 1024);
    split_f32<<<3072, 256, 0, stream>>>(Wqkv, Wqh, Wql, 768 * 1024);
    split_f32<<<1024, 256, 0, stream>>>(Wproj, Wph, nullptr, 256 * 1024);

    gemm<0><<<dim3(24, 32, 1), 256, 0, stream>>>(
        xh, xl, Wqh, Wql, nullptr, bqkv, nullptr, qh, ql, kh, kl, vT,
        4096, 3072, 1024, 1024, 1024, 0LL, 0LL);
    fused_attn<<<dim3(BB * HH * 32), 512, 0, stream>>>(
        qh, ql, kh, kl, vT, attnF, ao);
    gemm<3><<<dim3(8, 32, 1), 256, 0, stream>>>(
        ao, nullptr, Wph, nullptr, nullptr, bproj, out, nullptr, nullptr, nullptr, nullptr, nullptr,
        4096, 1024, 1024, 1024, 1024, 0LL, 0LL);
    return;
  }

  // per-batch: 7M shared + 8M per-batch = 15M elems = 30MB
  __hip_bfloat16 *Wqh = w, *Wql = Wqh + 3 * M1, *Wph = Wql + 3 * M1;
  __hip_bfloat16 *xh = Wph + M1, *xl = xh + M1;
  __hip_bfloat16 *qh = xl + M1, *ql = qh + M1, *kh = ql + M1, *kl = kh + M1;
  __hip_bfloat16 *vT = kl + M1, *ao = vT + M1;

  split_f32<<<3072, 256, 0, stream>>>(Wqkv, Wqh, Wql, 768 * 1024);
  split_f32<<<1024, 256, 0, stream>>>(Wproj, Wph, nullptr, 256 * 1024);

  for (int b = 0; b < BB; ++b) {
    const float* xb   = x + (size_t)b * SS * EE;
    float* attnb      = attnF + (size_t)b * HH * SS * SS;
    float* outb       = out + (size_t)b * SS * EE;

    split_f32<<<1024, 256, 0, stream>>>(xb, xh, xl, 256 * 1024);
    gemm<0><<<dim3(24, 8, 1), 256, 0, stream>>>(
        xh, xl, Wqh, Wql, nullptr, bqkv, nullptr, qh, ql, kh, kl, vT,
        1024, 3072, 1024, 1024, 1024, 0LL, 0LL);
    fused_attn<<<dim3(HH * 32), 512, 0, stream>>>(
        qh, ql, kh, kl, vT, attnb, ao);
    gemm<3><<<dim3(8, 8, 1), 256, 0, stream>>>(
        ao, nullptr, Wph, nullptr, nullptr, bproj, outb, nullptr, nullptr, nullptr, nullptr, nullptr,
        1024, 1024, 1024, 1024, 1024, 0LL, 0LL);
  }
}

// Round 5
// 649.943 us; speedup vs baseline: 1.0315x; 1.0315x over previous
//
#include <hip/hip_runtime.h>
#include <hip/hip_bf16.h>
#include <cstdint>

// B=4, S=1024, E=1024, H=16, D=64.
// d_out = [ out (4M floats) | filtered_attn (64M floats) ].
// Pipeline: split_w -> gemm_qkv (QKV proj: A=x f32 staged+split in LDS,
// B=W hi/lo fragments DIRECT from L2; Q pre-scaled 1/8) -> fused_attn
// (QK^T + softmax/filter + PV; logits register-resident; QBLK=32)
// -> gemm_out (out proj).

#define BB 4
#define SS 1024
#define EE 1024
#define HH 16
#define DD 64

typedef __attribute__((ext_vector_type(8))) short bf16x8;
typedef __attribute__((ext_vector_type(4))) float f32x4;

// ---------------------------------------------------------------------------
// split_w: one launch. Wqkv -> (Wqh, Wql) split; Wproj -> Wph (hi only).
// grid = (768K + 256K) float4s / 256 = 4096 blocks.
// ---------------------------------------------------------------------------
__global__ __launch_bounds__(256) void split_w(
    const float* __restrict__ Wqkv, const float* __restrict__ Wproj,
    __hip_bfloat16* __restrict__ Wqh, __hip_bfloat16* __restrict__ Wql,
    __hip_bfloat16* __restrict__ Wph) {
  int i = blockIdx.x * 256 + threadIdx.x;
  const int NQ4 = 768 * 1024;
  if (i < NQ4) {
    float4 v = ((const float4*)Wqkv)[i];
    float vv[4] = {v.x, v.y, v.z, v.w};
    __hip_bfloat16 h[4], l[4];
#pragma unroll
    for (int j = 0; j < 4; ++j) {
      h[j] = __float2bfloat16(vv[j]);
      l[j] = __float2bfloat16(vv[j] - __bfloat162float(h[j]));
    }
    ((ushort4*)Wqh)[i] = *(ushort4*)h;
    ((ushort4*)Wql)[i] = *(ushort4*)l;
  } else {
    int j4 = i - NQ4;
    float4 v = ((const float4*)Wproj)[j4];
    __hip_bfloat16 h[4];
    h[0] = __float2bfloat16(v.x); h[1] = __float2bfloat16(v.y);
    h[2] = __float2bfloat16(v.z); h[3] = __float2bfloat16(v.w);
    ((ushort4*)Wph)[j4] = *(ushort4*)h;
  }
}

// ---------------------------------------------------------------------------
// gemm_qkv: C[m][n] = sum_k X[m][k]*W[n][k] + bias, split-bf16 (3 MFMA).
// A (x, f32) is staged into LDS with the hi/lo split computed in-register
// (bit-identical to the old split_f32 + bf16 staging). B (W hi/lo) fragments
// are read DIRECTLY from global: per n0-block the 512 KB B-panel is L2-hot
// (grid linear id % 8 pins an n-column to one XCD). LDS 36.9 KB (was 73.7).
// Outputs: qh,ql,kh,kl [B,H,S,D] (Q pre-scaled 0.125), vT [B,H,D,S].
// ---------------------------------------------------------------------------
__global__ __launch_bounds__(256) void gemm_qkv(
    const float* __restrict__ X, const __hip_bfloat16* __restrict__ Wh,
    const __hip_bfloat16* __restrict__ Wl, const float* __restrict__ bias,
    __hip_bfloat16* __restrict__ o1, __hip_bfloat16* __restrict__ o2,
    __hip_bfloat16* __restrict__ o3, __hip_bfloat16* __restrict__ o4,
    __hip_bfloat16* __restrict__ o5, int M) {
  const int tid  = threadIdx.x;
  const int lane = tid & 63;
  const int wave = tid >> 6;
  const int wm   = (wave >> 1) * 64;
  const int wn   = (wave & 1) * 64;
  const int quad = lane >> 4;
  const int l15  = lane & 15;
  const int m0   = blockIdx.y * 128;
  const int n0   = blockIdx.x * 128;

  __shared__ __align__(16) __hip_bfloat16 lAh[128 * 72];
  __shared__ __align__(16) __hip_bfloat16 lAl[128 * 72];

  f32x4 acc[4][4] = {};
  const __hip_bfloat16* pBh = Wh + (long long)(n0 + wn + l15) * 1024 + quad * 8;
  const __hip_bfloat16* pBl = Wl + (long long)(n0 + wn + l15) * 1024 + quad * 8;

  for (int k0 = 0; k0 < 1024; k0 += 64) {
#pragma unroll
    for (int it = 0; it < 4; ++it) {
      int flat = (it * 256 + tid) * 8;
      int row  = flat >> 6;
      int kk   = flat & 63;
      const float* src = X + (long long)(m0 + row) * 1024 + k0 + kk;
      float4 f0 = *(const float4*)src;
      float4 f1 = *(const float4*)(src + 4);
      float vv[8] = {f0.x, f0.y, f0.z, f0.w, f1.x, f1.y, f1.z, f1.w};
      __hip_bfloat16 t[8], u[8];
#pragma unroll
      for (int j2 = 0; j2 < 8; ++j2) {
        t[j2] = __float2bfloat16(vv[j2]);
        u[j2] = __float2bfloat16(vv[j2] - __bfloat162float(t[j2]));
      }
      *(uint4*)&lAh[row * 72 + kk] = *(uint4*)t;
      *(uint4*)&lAl[row * 72 + kk] = *(uint4*)u;
    }
    __syncthreads();

#pragma unroll
    for (int ks = 0; ks < 64; ks += 32) {
      bf16x8 ah[4], al[4], bh[4], bl[4];
#pragma unroll
      for (int i = 0; i < 4; ++i) {
        int off = (wm + i * 16 + l15) * 72 + ks + quad * 8;
        ah[i] = *(const bf16x8*)&lAh[off];
        al[i] = *(const bf16x8*)&lAl[off];
      }
#pragma unroll
      for (int j = 0; j < 4; ++j) {
        const long long boff = (long long)j * 16 * 1024 + k0 + ks;
        bh[j] = *(const bf16x8*)(pBh + boff);
        bl[j] = *(const bf16x8*)(pBl + boff);
      }
#pragma unroll
      for (int i = 0; i < 4; ++i)
#pragma unroll
        for (int j = 0; j < 4; ++j) {
          acc[i][j] = __builtin_amdgcn_mfma_f32_16x16x32_bf16(al[i], bh[j], acc[i][j], 0, 0, 0);
          acc[i][j] = __builtin_amdgcn_mfma_f32_16x16x32_bf16(ah[i], bl[j], acc[i][j], 0, 0, 0);
          acc[i][j] = __builtin_amdgcn_mfma_f32_16x16x32_bf16(ah[i], bh[j], acc[i][j], 0, 0, 0);
        }
    }
    __syncthreads();
  }

  // C/D layout: col = lane&15, row = quad*4 + reg
#pragma unroll
  for (int i = 0; i < 4; ++i) {
#pragma unroll
    for (int j = 0; j < 4; ++j) {
#pragma unroll
      for (int r = 0; r < 4; ++r) {
        int m = m0 + wm + i * 16 + quad * 4 + r;
        int n = n0 + wn + j * 16 + l15;
        float v = acc[i][j][r] + bias[n];
        int c = n >> 10, nn = n & 1023, h = nn >> 6, d = nn & 63;
        int b = m >> 10, s = m & 1023;
        long long idx = (((long long)(b * HH + h) * SS + s) << 6) + d;
        if (c == 0) {
          v *= 0.125f;  // fold D^-0.5 into Q (exact pow2)
          __hip_bfloat16 hh = __float2bfloat16(v);
          o1[idx] = hh;
          o2[idx] = __float2bfloat16(v - __bfloat162float(hh));
        } else if (c == 1) {
          __hip_bfloat16 hh = __float2bfloat16(v);
          o3[idx] = hh;
          o4[idx] = __float2bfloat16(v - __bfloat162float(hh));
        } else {
          o5[(((long long)(b * HH + h) * DD + d) << 10) + s] = __float2bfloat16(v);
        }
      }
    }
  }
}

// ---------------------------------------------------------------------------
// gemm_out: out[m][n] = sum_k ao[m][k]*Wph[n][k] + bias[n]. Plain bf16,
// both operands LDS-staged (old MODE 3, unchanged behavior).
// ---------------------------------------------------------------------------
__global__ __launch_bounds__(256) void gemm_out(
    const __hip_bfloat16* __restrict__ Ah, const __hip_bfloat16* __restrict__ Bh,
    const float* __restrict__ bias, float* __restrict__ oF, int M) {
  const int tid  = threadIdx.x;
  const int lane = tid & 63;
  const int wave = tid >> 6;
  const int wm   = (wave >> 1) * 64;
  const int wn   = (wave & 1) * 64;
  const int quad = lane >> 4;
  const int l15  = lane & 15;
  const int m0   = blockIdx.y * 128;
  const int n0   = blockIdx.x * 128;

  __shared__ __align__(16) __hip_bfloat16 lds[2 * 128 * 72];
  __hip_bfloat16* lA = lds;
  __hip_bfloat16* lB = lds + 128 * 72;

  f32x4 acc[4][4] = {};

  for (int k0 = 0; k0 < 1024; k0 += 64) {
#pragma unroll
    for (int it = 0; it < 4; ++it) {
      int flat = (it * 256 + tid) * 8;
      int row  = flat >> 6;
      int kk   = flat & 63;
      uint4 va = *(const uint4*)(Ah + (long long)(m0 + row) * 1024 + k0 + kk);
      *(uint4*)&lA[row * 72 + kk] = va;
      uint4 vb = *(const uint4*)(Bh + (long long)(n0 + row) * 1024 + k0 + kk);
      *(uint4*)&lB[row * 72 + kk] = vb;
    }
    __syncthreads();

#pragma unroll
    for (int ks = 0; ks < 64; ks += 32) {
      bf16x8 ah[4], bh[4];
#pragma unroll
      for (int i = 0; i < 4; ++i)
        ah[i] = *(const bf16x8*)&lA[(wm + i * 16 + l15) * 72 + ks + quad * 8];
#pragma unroll
      for (int j = 0; j < 4; ++j)
        bh[j] = *(const bf16x8*)&lB[(wn + j * 16 + l15) * 72 + ks + quad * 8];
#pragma unroll
      for (int i = 0; i < 4; ++i)
#pragma unroll
        for (int j = 0; j < 4; ++j)
          acc[i][j] = __builtin_amdgcn_mfma_f32_16x16x32_bf16(ah[i], bh[j], acc[i][j], 0, 0, 0);
    }
    __syncthreads();
  }

#pragma unroll
  for (int i = 0; i < 4; ++i)
#pragma unroll
    for (int j = 0; j < 4; ++j)
#pragma unroll
      for (int r = 0; r < 4; ++r) {
        int m = m0 + wm + i * 16 + quad * 4 + r;
        int n = n0 + wn + j * 16 + l15;
        oF[(long long)m * EE + n] = acc[i][j][r] + bias[n];
      }
}

// ---------------------------------------------------------------------------
// 16-lane-group reductions (lanes quad*16 .. quad*16+15; xor<=8 stays in group)
// ---------------------------------------------------------------------------
__device__ __forceinline__ float qg_max16(float v) {
#pragma unroll
  for (int o = 8; o > 0; o >>= 1) v = fmaxf(v, __shfl_xor(v, o));
  return v;
}
__device__ __forceinline__ float qg_sum16(float v) {
#pragma unroll
  for (int o = 8; o > 0; o >>= 1) v += __shfl_xor(v, o);
  return v;
}

// ---------------------------------------------------------------------------
// fused_attn v4 (unchanged from round 4): one block per (bh, 32-row Q tile).
// 8 waves / 512 threads; logits register-resident; K frags loaded once feed
// both 16-row strips; division-free filter; Pl bf16 tile for PV; Obuf
// cross-wave partial-O combine. LDS 77.8 KB; launch_bounds(512,4).
// ---------------------------------------------------------------------------
__global__ __launch_bounds__(512, 4) void fused_attn(
    const __hip_bfloat16* __restrict__ qh, const __hip_bfloat16* __restrict__ ql,
    const __hip_bfloat16* __restrict__ kh, const __hip_bfloat16* __restrict__ kl,
    const __hip_bfloat16* __restrict__ vT, float* __restrict__ attn,
    __hip_bfloat16* __restrict__ ao) {
  const int tid  = threadIdx.x;
  const int lane = tid & 63;
  const int wave = tid >> 6;   // 0..7
  const int quad = lane >> 4;
  const int l15  = lane & 15;

  // XCD-chunked swizzle (gridDim.x is a multiple of 8 -> bijective)
  int id = blockIdx.x;
  const int q8 = gridDim.x >> 3;
  id = (id & 7) * q8 + (id >> 3);
  const int bh = id >> 5;          // 32 Q-tiles per bh
  const int q0 = (id & 31) * 32;

  const int brow = (bh >> 4) * SS;   // 0 in per-batch mode (bh = h < 16)
  const int h    = bh & 15;
  const long long qbase = ((long long)bh * SS + q0) * DD;
  const long long kbase = (long long)bh * SS * DD;
  const long long vbase = (long long)bh * DD * SS;
  const long long abase = ((long long)bh * SS + q0) * SS;

  __shared__ __align__(16) __hip_bfloat16 Pl[32][1032];  // 66,048 B
  __shared__ float red[3][8][32];                        //  3,072 B
  __shared__ float Obuf[4][32][17];                      //  8,704 B

  // --- Q A-frags for both strips (row l15 + s*16, k-cols quad*8, +32) ---
  bf16x8 aqh0[2], aqh1[2], aql0[2], aql1[2];   // [strip]
#pragma unroll
  for (int s = 0; s < 2; ++s) {
    const __hip_bfloat16* ph = qh + qbase + (s * 16 + l15) * DD + quad * 8;
    const __hip_bfloat16* pl = ql + qbase + (s * 16 + l15) * DD + quad * 8;
    aqh0[s] = *(const bf16x8*)(ph);
    aqh1[s] = *(const bf16x8*)(ph + 32);
    aql0[s] = *(const bf16x8*)(pl);
    aql1[s] = *(const bf16x8*)(pl + 32);
  }

  // --- Phase 1: QK^T, register-resident; wave owns k in [wave*128,+128) ---
  f32x4 acc0[8], acc1[8];
  const __hip_bfloat16* pkh0 = kh + kbase + (long long)(wave * 128 + l15) * DD + quad * 8;
  const __hip_bfloat16* pkl0 = kl + kbase + (long long)(wave * 128 + l15) * DD + quad * 8;
#pragma unroll
  for (int nt = 0; nt < 8; ++nt) {
    const __hip_bfloat16* pkh = pkh0 + nt * 16 * DD;
    const __hip_bfloat16* pkl = pkl0 + nt * 16 * DD;
    f32x4 a0 = {}, a1 = {};
    {  // kc = 0 (k 0..31 of D)
      bf16x8 b = *(const bf16x8*)(pkh);
      bf16x8 c = *(const bf16x8*)(pkl);
      __builtin_amdgcn_s_setprio(1);
      a0 = __builtin_amdgcn_mfma_f32_16x16x32_bf16(aql0[0], b, a0, 0, 0, 0);
      a1 = __builtin_amdgcn_mfma_f32_16x16x32_bf16(aql0[1], b, a1, 0, 0, 0);
      a0 = __builtin_amdgcn_mfma_f32_16x16x32_bf16(aqh0[0], c, a0, 0, 0, 0);
      a1 = __builtin_amdgcn_mfma_f32_16x16x32_bf16(aqh0[1], c, a1, 0, 0, 0);
      a0 = __builtin_amdgcn_mfma_f32_16x16x32_bf16(aqh0[0], b, a0, 0, 0, 0);
      a1 = __builtin_amdgcn_mfma_f32_16x16x32_bf16(aqh0[1], b, a1, 0, 0, 0);
      __builtin_amdgcn_s_setprio(0);
    }
    {  // kc = 1 (k 32..63 of D)
      bf16x8 b = *(const bf16x8*)(pkh + 32);
      bf16x8 c = *(const bf16x8*)(pkl + 32);
      __builtin_amdgcn_s_setprio(1);
      a0 = __builtin_amdgcn_mfma_f32_16x16x32_bf16(aql1[0], b, a0, 0, 0, 0);
      a1 = __builtin_amdgcn_mfma_f32_16x16x32_bf16(aql1[1], b, a1, 0, 0, 0);
      a0 = __builtin_amdgcn_mfma_f32_16x16x32_bf16(aqh1[0], c, a0, 0, 0, 0);
      a1 = __builtin_amdgcn_mfma_f32_16x16x32_bf16(aqh1[1], c, a1, 0, 0, 0);
      a0 = __builtin_amdgcn_mfma_f32_16x16x32_bf16(aqh1[0], b, a0, 0, 0, 0);
      a1 = __builtin_amdgcn_mfma_f32_16x16x32_bf16(aqh1[1], b, a1, 0, 0, 0);
      __builtin_amdgcn_s_setprio(0);
    }
    acc0[nt] = a0;
    acc1[nt] = a1;
  }
  // (Q was pre-scaled by 0.125 in gemm_qkv; logits already scaled.)

  // --- row max per strip: lane tree over nt -> l15-group -> cross-wave ---
  {
    float mx0[4], mx1[4];
#pragma unroll
    for (int r = 0; r < 4; ++r) {
      float a = fmaxf(fmaxf(fmaxf(acc0[0][r], acc0[1][r]), fmaxf(acc0[2][r], acc0[3][r])),
                      fmaxf(fmaxf(acc0[4][r], acc0[5][r]), fmaxf(acc0[6][r], acc0[7][r])));
      mx0[r] = qg_max16(a);
      float b = fmaxf(fmaxf(fmaxf(acc1[0][r], acc1[1][r]), fmaxf(acc1[2][r], acc1[3][r])),
                      fmaxf(fmaxf(acc1[4][r], acc1[5][r]), fmaxf(acc1[6][r], acc1[7][r])));
      mx1[r] = qg_max16(b);
    }
    if (l15 == 0) {
#pragma unroll
      for (int r = 0; r < 4; ++r) {
        red[0][wave][quad * 4 + r]      = mx0[r];
        red[0][wave][16 + quad * 4 + r] = mx1[r];
      }
    }
  }
  __syncthreads();
  float m0[4], m1[4];
#pragma unroll
  for (int r = 0; r < 4; ++r) {
    const int q = quad * 4 + r;
    m0[r] = fmaxf(fmaxf(fmaxf(red[0][0][q], red[0][1][q]), fmaxf(red[0][2][q], red[0][3][q])),
                  fmaxf(fmaxf(red[0][4][q], red[0][5][q]), fmaxf(red[0][6][q], red[0][7][q])));
    m1[r] = fmaxf(fmaxf(fmaxf(red[0][0][16 + q], red[0][1][16 + q]), fmaxf(red[0][2][16 + q], red[0][3][16 + q])),
                  fmaxf(fmaxf(red[0][4][16 + q], red[0][5][16 + q]), fmaxf(red[0][6][16 + q], red[0][7][16 + q])));
  }

  // --- e = exp(v - m), Z ---
  {
    float z0[4] = {0.f, 0.f, 0.f, 0.f}, z1[4] = {0.f, 0.f, 0.f, 0.f};
#pragma unroll
    for (int nt = 0; nt < 8; ++nt)
#pragma unroll
      for (int r = 0; r < 4; ++r) {
        float e0 = expf(acc0[nt][r] - m0[r]);
        acc0[nt][r] = e0; z0[r] += e0;
        float e1 = expf(acc1[nt][r] - m1[r]);
        acc1[nt][r] = e1; z1[r] += e1;
      }
#pragma unroll
    for (int r = 0; r < 4; ++r) { z0[r] = qg_sum16(z0[r]); z1[r] = qg_sum16(z1[r]); }
    if (l15 == 0) {
#pragma unroll
      for (int r = 0; r < 4; ++r) {
        red[1][wave][quad * 4 + r]      = z0[r];
        red[1][wave][16 + quad * 4 + r] = z1[r];
      }
    }
  }
  __syncthreads();
  float c0[4], c1[4];
#pragma unroll
  for (int r = 0; r < 4; ++r) {
    const int q = quad * 4 + r;
    const float Z0 = ((red[1][0][q] + red[1][1][q]) + (red[1][2][q] + red[1][3][q])) +
                     ((red[1][4][q] + red[1][5][q]) + (red[1][6][q] + red[1][7][q]));
    const float Z1 = ((red[1][0][16 + q] + red[1][1][16 + q]) + (red[1][2][16 + q] + red[1][3][16 + q])) +
                     ((red[1][4][16 + q] + red[1][5][16 + q]) + (red[1][6][16 + q] + red[1][7][16 + q]));
    c0[r] = 4e-4f * Z0;   // sel: e > c  <=>  e/Z > 4e-4
    c1[r] = 4e-4f * Z1;
  }

  // --- Zs = sum of selected e ---
  {
    float s0[4] = {0.f, 0.f, 0.f, 0.f}, s1[4] = {0.f, 0.f, 0.f, 0.f};
#pragma unroll
    for (int nt = 0; nt < 8; ++nt)
#pragma unroll
      for (int r = 0; r < 4; ++r) {
        if (acc0[nt][r] > c0[r]) s0[r] += acc0[nt][r];
        if (acc1[nt][r] > c1[r]) s1[r] += acc1[nt][r];
      }
#pragma unroll
    for (int r = 0; r < 4; ++r) { s0[r] = qg_sum16(s0[r]); s1[r] = qg_sum16(s1[r]); }
    if (l15 == 0) {
#pragma unroll
      for (int r = 0; r < 4; ++r) {
        red[2][wave][quad * 4 + r]      = s0[r];
        red[2][wave][16 + quad * 4 + r] = s1[r];
      }
    }
  }
  __syncthreads();
  float rinv0[4], rinv1[4];
#pragma unroll
  for (int r = 0; r < 4; ++r) {
    const int q = quad * 4 + r;
    const float Zs0 = ((red[2][0][q] + red[2][1][q]) + (red[2][2][q] + red[2][3][q])) +
                      ((red[2][4][q] + red[2][5][q]) + (red[2][6][q] + red[2][7][q]));
    const float Zs1 = ((red[2][0][16 + q] + red[2][1][16 + q]) + (red[2][2][16 + q] + red[2][3][16 + q])) +
                      ((red[2][4][16 + q] + red[2][5][16 + q]) + (red[2][6][16 + q] + red[2][7][16 + q]));
    rinv0[r] = 1.0f / Zs0;   // row max always selected -> Zs >= 1
    rinv1[r] = 1.0f / Zs1;
  }

  // --- write filtered probs: f32 -> global (required), bf16 -> LDS (P) ---
#pragma unroll
  for (int nt = 0; nt < 8; ++nt) {
    const int k = wave * 128 + nt * 16 + l15;
#pragma unroll
    for (int r = 0; r < 4; ++r) {
      const int q = quad * 4 + r;
      const float e0 = acc0[nt][r];
      const float p0 = (e0 > c0[r]) ? e0 * rinv0[r] : 0.f;
      attn[abase + (long long)q * SS + k] = p0;
      Pl[q][k] = __float2bfloat16(p0);
      const float e1 = acc1[nt][r];
      const float p1 = (e1 > c1[r]) ? e1 * rinv1[r] : 0.f;
      attn[abase + (long long)(16 + q) * SS + k] = p1;
      Pl[16 + q][k] = __float2bfloat16(p1);
    }
  }
  __syncthreads();

  // --- Phase 3: PV. wave -> d-group (w&3)*16, k-half (w>>2)*512, 2 strips ---
  const int d0  = (wave & 3) * 16;
  const int kh2 = (wave >> 2) * 512;
  f32x4 oA0 = {}, oA1 = {}, oB0 = {}, oB1 = {};
  const __hip_bfloat16* pv  = vT + vbase + (long long)(d0 + l15) * SS + kh2 + quad * 8;
  const __hip_bfloat16* pp0 = &Pl[l15][kh2] + quad * 8;
  const __hip_bfloat16* pp1 = &Pl[16 + l15][kh2] + quad * 8;
#pragma unroll
  for (int ks = 0; ks < 16; ks += 2) {
    bf16x8 v0  = *(const bf16x8*)(pv + ks * 32);
    bf16x8 v1  = *(const bf16x8*)(pv + (ks + 1) * 32);
    bf16x8 a00 = *(const bf16x8*)(pp0 + ks * 32);
    bf16x8 a01 = *(const bf16x8*)(pp0 + (ks + 1) * 32);
    bf16x8 a10 = *(const bf16x8*)(pp1 + ks * 32);
    bf16x8 a11 = *(const bf16x8*)(pp1 + (ks + 1) * 32);
    __builtin_amdgcn_s_setprio(1);
    oA0 = __builtin_amdgcn_mfma_f32_16x16x32_bf16(a00, v0, oA0, 0, 0, 0);
    oB0 = __builtin_amdgcn_mfma_f32_16x16x32_bf16(a10, v0, oB0, 0, 0, 0);
    oA1 = __builtin_amdgcn_mfma_f32_16x16x32_bf16(a01, v1, oA1, 0, 0, 0);
    oB1 = __builtin_amdgcn_mfma_f32_16x16x32_bf16(a11, v1, oB1, 0, 0, 0);
    __builtin_amdgcn_s_setprio(0);
  }
  float oS0[4], oS1[4];
#pragma unroll
  for (int r = 0; r < 4; ++r) { oS0[r] = oA0[r] + oA1[r]; oS1[r] = oB0[r] + oB1[r]; }

  if (wave >= 4) {
#pragma unroll
    for (int r = 0; r < 4; ++r) {
      Obuf[wave & 3][quad * 4 + r][l15]      = oS0[r];
      Obuf[wave & 3][16 + quad * 4 + r][l15] = oS1[r];
    }
  }
  __syncthreads();
  if (wave < 4) {
    // C: row(q) = quad*4+r, col(d) = l15
#pragma unroll
    for (int r = 0; r < 4; ++r) {
      const int qA = q0 + quad * 4 + r;
      const int qB = qA + 16;
      const float vA = oS0[r] + Obuf[wave][quad * 4 + r][l15];
      const float vB = oS1[r] + Obuf[wave][16 + quad * 4 + r][l15];
      ao[((long long)(brow + qA)) * EE + h * DD + d0 + l15] = __float2bfloat16(vA);
      ao[((long long)(brow + qB)) * EE + h * DD + d0 + l15] = __float2bfloat16(vB);
    }
  }
}

// ---------------------------------------------------------------------------
extern "C" void kernel_launch(void* const* d_in, const int* in_sizes, int n_in,
                              void* d_out, int out_size, void* d_ws, size_t ws_size,
                              hipStream_t stream) {
  const float* x     = (const float*)d_in[0];  // [4,1024,1024]
  const float* Wqkv  = (const float*)d_in[1];  // [3072,1024]
  const float* bqkv  = (const float*)d_in[2];  // [3072]
  const float* Wproj = (const float*)d_in[3];  // [1024,1024]
  const float* bproj = (const float*)d_in[4];  // [1024]

  float* out   = (float*)d_out;                        // 4M floats
  float* attnF = out + (size_t)BB * SS * EE;           // 64M floats

  const size_t M1 = 1024 * 1024;
  __hip_bfloat16* w = (__hip_bfloat16*)d_ws;

  if (ws_size >= (size_t)80 * 1024 * 1024) {
    // flat: Wqh 3M, Wql 3M, Wph 1M, qh/ql/kh/kl 4M each, vT 4M, ao 4M = 31M elems = 62MB
    __hip_bfloat16 *Wqh = w, *Wql = Wqh + 3 * M1, *Wph = Wql + 3 * M1;
    __hip_bfloat16 *qh = Wph + M1, *ql = qh + 4 * M1, *kh = ql + 4 * M1, *kl = kh + 4 * M1;
    __hip_bfloat16 *vT = kl + 4 * M1, *ao = vT + 4 * M1;

    split_w<<<4096, 256, 0, stream>>>(Wqkv, Wproj, Wqh, Wql, Wph);
    gemm_qkv<<<dim3(24, 32), 256, 0, stream>>>(
        x, Wqh, Wql, bqkv, qh, ql, kh, kl, vT, 4096);
    fused_attn<<<dim3(BB * HH * 32), 512, 0, stream>>>(
        qh, ql, kh, kl, vT, attnF, ao);
    gemm_out<<<dim3(8, 32), 256, 0, stream>>>(ao, Wph, bproj, out, 4096);
    return;
  }

  // per-batch: 7M shared + 6M per-batch = 13M elems = 26MB
  __hip_bfloat16 *Wqh = w, *Wql = Wqh + 3 * M1, *Wph = Wql + 3 * M1;
  __hip_bfloat16 *qh = Wph + M1, *ql = qh + M1, *kh = ql + M1, *kl = kh + M1;
  __hip_bfloat16 *vT = kl + M1, *ao = vT + M1;

  split_w<<<4096, 256, 0, stream>>>(Wqkv, Wproj, Wqh, Wql, Wph);

  for (int b = 0; b < BB; ++b) {
    const float* xb   = x + (size_t)b * SS * EE;
    float* attnb      = attnF + (size_t)b * HH * SS * SS;
    float* outb       = out + (size_t)b * SS * EE;

    gemm_qkv<<<dim3(24, 8), 256, 0, stream>>>(
        xb, Wqh, Wql, bqkv, qh, ql, kh, kl, vT, 1024);
    fused_attn<<<dim3(HH * 32), 512, 0, stream>>>(
        qh, ql, kh, kl, vT, attnb, ao);
    gemm_out<<<dim3(8, 8), 256, 0, stream>>>(ao, Wph, bproj, outb, 1024);
  }
}

// Round 6
// 646.573 us; speedup vs baseline: 1.0369x; 1.0052x over previous
//
#include <hip/hip_runtime.h>
#include <hip/hip_bf16.h>
#include <cstdint>

// B=4, S=1024, E=1024, H=16, D=64.
// d_out = [ out (4M floats) | filtered_attn (64M floats) ].
// Pipeline: split_w -> gemm_qkv (QKV proj: A=x f32 staged+split in LDS,
// B=W hi/lo fragments DIRECT from L2; Q pre-scaled 1/8) -> fused_attn v5
// (QK^T + softmax/filter + PV; logits register-resident; QBLK=32; 3 barriers;
//  unnormalized-P PV with post-scale; attn stores overlap PV) -> gemm_out.

#define BB 4
#define SS 1024
#define EE 1024
#define HH 16
#define DD 64

typedef __attribute__((ext_vector_type(8))) short bf16x8;
typedef __attribute__((ext_vector_type(4))) float f32x4;

// ---------------------------------------------------------------------------
// split_w: one launch. Wqkv -> (Wqh, Wql) split; Wproj -> Wph (hi only).
// grid = (768K + 256K) float4s / 256 = 4096 blocks.
// ---------------------------------------------------------------------------
__global__ __launch_bounds__(256) void split_w(
    const float* __restrict__ Wqkv, const float* __restrict__ Wproj,
    __hip_bfloat16* __restrict__ Wqh, __hip_bfloat16* __restrict__ Wql,
    __hip_bfloat16* __restrict__ Wph) {
  int i = blockIdx.x * 256 + threadIdx.x;
  const int NQ4 = 768 * 1024;
  if (i < NQ4) {
    float4 v = ((const float4*)Wqkv)[i];
    float vv[4] = {v.x, v.y, v.z, v.w};
    __hip_bfloat16 h[4], l[4];
#pragma unroll
    for (int j = 0; j < 4; ++j) {
      h[j] = __float2bfloat16(vv[j]);
      l[j] = __float2bfloat16(vv[j] - __bfloat162float(h[j]));
    }
    ((ushort4*)Wqh)[i] = *(ushort4*)h;
    ((ushort4*)Wql)[i] = *(ushort4*)l;
  } else {
    int j4 = i - NQ4;
    float4 v = ((const float4*)Wproj)[j4];
    __hip_bfloat16 h[4];
    h[0] = __float2bfloat16(v.x); h[1] = __float2bfloat16(v.y);
    h[2] = __float2bfloat16(v.z); h[3] = __float2bfloat16(v.w);
    ((ushort4*)Wph)[j4] = *(ushort4*)h;
  }
}

// ---------------------------------------------------------------------------
// gemm_qkv: C[m][n] = sum_k X[m][k]*W[n][k] + bias, split-bf16 (3 MFMA).
// A (x, f32) staged into LDS with hi/lo split in-register. B (W hi/lo)
// fragments read DIRECTLY from global (L2-hot per n0-panel).
// Outputs: qh,ql,kh,kl [B,H,S,D] (Q pre-scaled 0.125), vT [B,H,D,S].
// ---------------------------------------------------------------------------
__global__ __launch_bounds__(256) void gemm_qkv(
    const float* __restrict__ X, const __hip_bfloat16* __restrict__ Wh,
    const __hip_bfloat16* __restrict__ Wl, const float* __restrict__ bias,
    __hip_bfloat16* __restrict__ o1, __hip_bfloat16* __restrict__ o2,
    __hip_bfloat16* __restrict__ o3, __hip_bfloat16* __restrict__ o4,
    __hip_bfloat16* __restrict__ o5, int M) {
  const int tid  = threadIdx.x;
  const int lane = tid & 63;
  const int wave = tid >> 6;
  const int wm   = (wave >> 1) * 64;
  const int wn   = (wave & 1) * 64;
  const int quad = lane >> 4;
  const int l15  = lane & 15;
  const int m0   = blockIdx.y * 128;
  const int n0   = blockIdx.x * 128;

  __shared__ __align__(16) __hip_bfloat16 lAh[128 * 72];
  __shared__ __align__(16) __hip_bfloat16 lAl[128 * 72];

  f32x4 acc[4][4] = {};
  const __hip_bfloat16* pBh = Wh + (long long)(n0 + wn + l15) * 1024 + quad * 8;
  const __hip_bfloat16* pBl = Wl + (long long)(n0 + wn + l15) * 1024 + quad * 8;

  for (int k0 = 0; k0 < 1024; k0 += 64) {
#pragma unroll
    for (int it = 0; it < 4; ++it) {
      int flat = (it * 256 + tid) * 8;
      int row  = flat >> 6;
      int kk   = flat & 63;
      const float* src = X + (long long)(m0 + row) * 1024 + k0 + kk;
      float4 f0 = *(const float4*)src;
      float4 f1 = *(const float4*)(src + 4);
      float vv[8] = {f0.x, f0.y, f0.z, f0.w, f1.x, f1.y, f1.z, f1.w};
      __hip_bfloat16 t[8], u[8];
#pragma unroll
      for (int j2 = 0; j2 < 8; ++j2) {
        t[j2] = __float2bfloat16(vv[j2]);
        u[j2] = __float2bfloat16(vv[j2] - __bfloat162float(t[j2]));
      }
      *(uint4*)&lAh[row * 72 + kk] = *(uint4*)t;
      *(uint4*)&lAl[row * 72 + kk] = *(uint4*)u;
    }
    __syncthreads();

#pragma unroll
    for (int ks = 0; ks < 64; ks += 32) {
      bf16x8 ah[4], al[4], bh[4], bl[4];
#pragma unroll
      for (int i = 0; i < 4; ++i) {
        int off = (wm + i * 16 + l15) * 72 + ks + quad * 8;
        ah[i] = *(const bf16x8*)&lAh[off];
        al[i] = *(const bf16x8*)&lAl[off];
      }
#pragma unroll
      for (int j = 0; j < 4; ++j) {
        const long long boff = (long long)j * 16 * 1024 + k0 + ks;
        bh[j] = *(const bf16x8*)(pBh + boff);
        bl[j] = *(const bf16x8*)(pBl + boff);
      }
#pragma unroll
      for (int i = 0; i < 4; ++i)
#pragma unroll
        for (int j = 0; j < 4; ++j) {
          acc[i][j] = __builtin_amdgcn_mfma_f32_16x16x32_bf16(al[i], bh[j], acc[i][j], 0, 0, 0);
          acc[i][j] = __builtin_amdgcn_mfma_f32_16x16x32_bf16(ah[i], bl[j], acc[i][j], 0, 0, 0);
          acc[i][j] = __builtin_amdgcn_mfma_f32_16x16x32_bf16(ah[i], bh[j], acc[i][j], 0, 0, 0);
        }
    }
    __syncthreads();
  }

  // C/D layout: col = lane&15, row = quad*4 + reg
#pragma unroll
  for (int i = 0; i < 4; ++i) {
#pragma unroll
    for (int j = 0; j < 4; ++j) {
#pragma unroll
      for (int r = 0; r < 4; ++r) {
        int m = m0 + wm + i * 16 + quad * 4 + r;
        int n = n0 + wn + j * 16 + l15;
        float v = acc[i][j][r] + bias[n];
        int c = n >> 10, nn = n & 1023, h = nn >> 6, d = nn & 63;
        int b = m >> 10, s = m & 1023;
        long long idx = (((long long)(b * HH + h) * SS + s) << 6) + d;
        if (c == 0) {
          v *= 0.125f;  // fold D^-0.5 into Q (exact pow2)
          __hip_bfloat16 hh = __float2bfloat16(v);
          o1[idx] = hh;
          o2[idx] = __float2bfloat16(v - __bfloat162float(hh));
        } else if (c == 1) {
          __hip_bfloat16 hh = __float2bfloat16(v);
          o3[idx] = hh;
          o4[idx] = __float2bfloat16(v - __bfloat162float(hh));
        } else {
          o5[(((long long)(b * HH + h) * DD + d) << 10) + s] = __float2bfloat16(v);
        }
      }
    }
  }
}

// ---------------------------------------------------------------------------
// gemm_out: out[m][n] = sum_k ao[m][k]*Wph[n][k] + bias[n]. Plain bf16.
// ---------------------------------------------------------------------------
__global__ __launch_bounds__(256) void gemm_out(
    const __hip_bfloat16* __restrict__ Ah, const __hip_bfloat16* __restrict__ Bh,
    const float* __restrict__ bias, float* __restrict__ oF, int M) {
  const int tid  = threadIdx.x;
  const int lane = tid & 63;
  const int wave = tid >> 6;
  const int wm   = (wave >> 1) * 64;
  const int wn   = (wave & 1) * 64;
  const int quad = lane >> 4;
  const int l15  = lane & 15;
  const int m0   = blockIdx.y * 128;
  const int n0   = blockIdx.x * 128;

  __shared__ __align__(16) __hip_bfloat16 lds[2 * 128 * 72];
  __hip_bfloat16* lA = lds;
  __hip_bfloat16* lB = lds + 128 * 72;

  f32x4 acc[4][4] = {};

  for (int k0 = 0; k0 < 1024; k0 += 64) {
#pragma unroll
    for (int it = 0; it < 4; ++it) {
      int flat = (it * 256 + tid) * 8;
      int row  = flat >> 6;
      int kk   = flat & 63;
      uint4 va = *(const uint4*)(Ah + (long long)(m0 + row) * 1024 + k0 + kk);
      *(uint4*)&lA[row * 72 + kk] = va;
      uint4 vb = *(const uint4*)(Bh + (long long)(n0 + row) * 1024 + k0 + kk);
      *(uint4*)&lB[row * 72 + kk] = vb;
    }
    __syncthreads();

#pragma unroll
    for (int ks = 0; ks < 64; ks += 32) {
      bf16x8 ah[4], bh[4];
#pragma unroll
      for (int i = 0; i < 4; ++i)
        ah[i] = *(const bf16x8*)&lA[(wm + i * 16 + l15) * 72 + ks + quad * 8];
#pragma unroll
      for (int j = 0; j < 4; ++j)
        bh[j] = *(const bf16x8*)&lB[(wn + j * 16 + l15) * 72 + ks + quad * 8];
#pragma unroll
      for (int i = 0; i < 4; ++i)
#pragma unroll
        for (int j = 0; j < 4; ++j)
          acc[i][j] = __builtin_amdgcn_mfma_f32_16x16x32_bf16(ah[i], bh[j], acc[i][j], 0, 0, 0);
    }
    __syncthreads();
  }

#pragma unroll
  for (int i = 0; i < 4; ++i)
#pragma unroll
    for (int j = 0; j < 4; ++j)
#pragma unroll
      for (int r = 0; r < 4; ++r) {
        int m = m0 + wm + i * 16 + quad * 4 + r;
        int n = n0 + wn + j * 16 + l15;
        oF[(long long)m * EE + n] = acc[i][j][r] + bias[n];
      }
}

// ---------------------------------------------------------------------------
// 16-lane-group reductions (lanes quad*16 .. quad*16+15; xor<=8 stays in group)
// ---------------------------------------------------------------------------
__device__ __forceinline__ float qg_max16(float v) {
#pragma unroll
  for (int o = 8; o > 0; o >>= 1) v = fmaxf(v, __shfl_xor(v, o));
  return v;
}
__device__ __forceinline__ float qg_sum16(float v) {
#pragma unroll
  for (int o = 8; o > 0; o >>= 1) v += __shfl_xor(v, o);
  return v;
}

// ---------------------------------------------------------------------------
// fused_attn v5: one block per (bh, 32-row Q tile). 8 waves / 512 threads.
// Phase 1: wave w owns k-cols [w*128,+128) for BOTH strips -> acc0[8],acc1[8].
// Softmax: 3 barriers (was 4):
//   B1 max exchange, B2 Z exchange -> c = 4e-4*Z,
//   then Zs partials -> red[2] AND unnormalized P -> Pl (bf16(e), sel-masked),
//   B3 covers both.
// Post-B3: rinv = 1/Zs from red[2]; attn stores p = e*rinv (identical values
//   to v4) issued BEFORE the PV loop so their drain overlaps PV compute; acc
//   dies here (register peak unchanged).
// PV: wave -> (strip = w&1, d-group = (w>>1)*16), FULL k=1024 per wave:
//   no Obuf, no extra barrier; O scaled by rinv post-MFMA (PV linear in P).
// LDS 69.1 KB (Pl 66 + red 3); 2 blocks/CU (reg-bound as before).
// ---------------------------------------------------------------------------
__global__ __launch_bounds__(512, 4) void fused_attn(
    const __hip_bfloat16* __restrict__ qh, const __hip_bfloat16* __restrict__ ql,
    const __hip_bfloat16* __restrict__ kh, const __hip_bfloat16* __restrict__ kl,
    const __hip_bfloat16* __restrict__ vT, float* __restrict__ attn,
    __hip_bfloat16* __restrict__ ao) {
  const int tid  = threadIdx.x;
  const int lane = tid & 63;
  const int wave = tid >> 6;   // 0..7
  const int quad = lane >> 4;
  const int l15  = lane & 15;

  // XCD-chunked swizzle (gridDim.x is a multiple of 8 -> bijective)
  int id = blockIdx.x;
  const int q8 = gridDim.x >> 3;
  id = (id & 7) * q8 + (id >> 3);
  const int bh = id >> 5;          // 32 Q-tiles per bh
  const int q0 = (id & 31) * 32;

  const int brow = (bh >> 4) * SS;   // 0 in per-batch mode (bh = h < 16)
  const int h    = bh & 15;
  const long long qbase = ((long long)bh * SS + q0) * DD;
  const long long kbase = (long long)bh * SS * DD;
  const long long vbase = (long long)bh * DD * SS;
  const long long abase = ((long long)bh * SS + q0) * SS;

  __shared__ __align__(16) __hip_bfloat16 Pl[32][1032];  // 66,048 B
  __shared__ float red[3][8][32];                        //  3,072 B

  // --- Q A-frags for both strips (row l15 + s*16, k-cols quad*8, +32) ---
  bf16x8 aqh0[2], aqh1[2], aql0[2], aql1[2];   // [strip]
#pragma unroll
  for (int s = 0; s < 2; ++s) {
    const __hip_bfloat16* ph = qh + qbase + (s * 16 + l15) * DD + quad * 8;
    const __hip_bfloat16* pl = ql + qbase + (s * 16 + l15) * DD + quad * 8;
    aqh0[s] = *(const bf16x8*)(ph);
    aqh1[s] = *(const bf16x8*)(ph + 32);
    aql0[s] = *(const bf16x8*)(pl);
    aql1[s] = *(const bf16x8*)(pl + 32);
  }

  // --- Phase 1: QK^T, register-resident; wave owns k in [wave*128,+128) ---
  f32x4 acc0[8], acc1[8];
  const __hip_bfloat16* pkh0 = kh + kbase + (long long)(wave * 128 + l15) * DD + quad * 8;
  const __hip_bfloat16* pkl0 = kl + kbase + (long long)(wave * 128 + l15) * DD + quad * 8;
#pragma unroll
  for (int nt = 0; nt < 8; ++nt) {
    const __hip_bfloat16* pkh = pkh0 + nt * 16 * DD;
    const __hip_bfloat16* pkl = pkl0 + nt * 16 * DD;
    f32x4 a0 = {}, a1 = {};
    {  // kc = 0 (k 0..31 of D)
      bf16x8 b = *(const bf16x8*)(pkh);
      bf16x8 c = *(const bf16x8*)(pkl);
      __builtin_amdgcn_s_setprio(1);
      a0 = __builtin_amdgcn_mfma_f32_16x16x32_bf16(aql0[0], b, a0, 0, 0, 0);
      a1 = __builtin_amdgcn_mfma_f32_16x16x32_bf16(aql0[1], b, a1, 0, 0, 0);
      a0 = __builtin_amdgcn_mfma_f32_16x16x32_bf16(aqh0[0], c, a0, 0, 0, 0);
      a1 = __builtin_amdgcn_mfma_f32_16x16x32_bf16(aqh0[1], c, a1, 0, 0, 0);
      a0 = __builtin_amdgcn_mfma_f32_16x16x32_bf16(aqh0[0], b, a0, 0, 0, 0);
      a1 = __builtin_amdgcn_mfma_f32_16x16x32_bf16(aqh0[1], b, a1, 0, 0, 0);
      __builtin_amdgcn_s_setprio(0);
    }
    {  // kc = 1 (k 32..63 of D)
      bf16x8 b = *(const bf16x8*)(pkh + 32);
      bf16x8 c = *(const bf16x8*)(pkl + 32);
      __builtin_amdgcn_s_setprio(1);
      a0 = __builtin_amdgcn_mfma_f32_16x16x32_bf16(aql1[0], b, a0, 0, 0, 0);
      a1 = __builtin_amdgcn_mfma_f32_16x16x32_bf16(aql1[1], b, a1, 0, 0, 0);
      a0 = __builtin_amdgcn_mfma_f32_16x16x32_bf16(aqh1[0], c, a0, 0, 0, 0);
      a1 = __builtin_amdgcn_mfma_f32_16x16x32_bf16(aqh1[1], c, a1, 0, 0, 0);
      a0 = __builtin_amdgcn_mfma_f32_16x16x32_bf16(aqh1[0], b, a0, 0, 0, 0);
      a1 = __builtin_amdgcn_mfma_f32_16x16x32_bf16(aqh1[1], b, a1, 0, 0, 0);
      __builtin_amdgcn_s_setprio(0);
    }
    acc0[nt] = a0;
    acc1[nt] = a1;
  }
  // (Q was pre-scaled by 0.125 in gemm_qkv; logits already scaled.)

  // --- row max per strip: lane tree over nt -> l15-group -> cross-wave ---
  {
    float mx0[4], mx1[4];
#pragma unroll
    for (int r = 0; r < 4; ++r) {
      float a = fmaxf(fmaxf(fmaxf(acc0[0][r], acc0[1][r]), fmaxf(acc0[2][r], acc0[3][r])),
                      fmaxf(fmaxf(acc0[4][r], acc0[5][r]), fmaxf(acc0[6][r], acc0[7][r])));
      mx0[r] = qg_max16(a);
      float b = fmaxf(fmaxf(fmaxf(acc1[0][r], acc1[1][r]), fmaxf(acc1[2][r], acc1[3][r])),
                      fmaxf(fmaxf(acc1[4][r], acc1[5][r]), fmaxf(acc1[6][r], acc1[7][r])));
      mx1[r] = qg_max16(b);
    }
    if (l15 == 0) {
#pragma unroll
      for (int r = 0; r < 4; ++r) {
        red[0][wave][quad * 4 + r]      = mx0[r];
        red[0][wave][16 + quad * 4 + r] = mx1[r];
      }
    }
  }
  __syncthreads();   // B1
  float m0[4], m1[4];
#pragma unroll
  for (int r = 0; r < 4; ++r) {
    const int q = quad * 4 + r;
    m0[r] = fmaxf(fmaxf(fmaxf(red[0][0][q], red[0][1][q]), fmaxf(red[0][2][q], red[0][3][q])),
                  fmaxf(fmaxf(red[0][4][q], red[0][5][q]), fmaxf(red[0][6][q], red[0][7][q])));
    m1[r] = fmaxf(fmaxf(fmaxf(red[0][0][16 + q], red[0][1][16 + q]), fmaxf(red[0][2][16 + q], red[0][3][16 + q])),
                  fmaxf(fmaxf(red[0][4][16 + q], red[0][5][16 + q]), fmaxf(red[0][6][16 + q], red[0][7][16 + q])));
  }

  // --- e = exp(v - m), Z ---
  {
    float z0[4] = {0.f, 0.f, 0.f, 0.f}, z1[4] = {0.f, 0.f, 0.f, 0.f};
#pragma unroll
    for (int nt = 0; nt < 8; ++nt)
#pragma unroll
      for (int r = 0; r < 4; ++r) {
        float e0 = expf(acc0[nt][r] - m0[r]);
        acc0[nt][r] = e0; z0[r] += e0;
        float e1 = expf(acc1[nt][r] - m1[r]);
        acc1[nt][r] = e1; z1[r] += e1;
      }
#pragma unroll
    for (int r = 0; r < 4; ++r) { z0[r] = qg_sum16(z0[r]); z1[r] = qg_sum16(z1[r]); }
    if (l15 == 0) {
#pragma unroll
      for (int r = 0; r < 4; ++r) {
        red[1][wave][quad * 4 + r]      = z0[r];
        red[1][wave][16 + quad * 4 + r] = z1[r];
      }
    }
  }
  __syncthreads();   // B2
  float c0[4], c1[4];
#pragma unroll
  for (int r = 0; r < 4; ++r) {
    const int q = quad * 4 + r;
    const float Z0 = ((red[1][0][q] + red[1][1][q]) + (red[1][2][q] + red[1][3][q])) +
                     ((red[1][4][q] + red[1][5][q]) + (red[1][6][q] + red[1][7][q]));
    const float Z1 = ((red[1][0][16 + q] + red[1][1][16 + q]) + (red[1][2][16 + q] + red[1][3][16 + q])) +
                     ((red[1][4][16 + q] + red[1][5][16 + q]) + (red[1][6][16 + q] + red[1][7][16 + q]));
    c0[r] = 4e-4f * Z0;   // sel: e > c  <=>  e/Z > 4e-4
    c1[r] = 4e-4f * Z1;
  }

  // --- Zs partials -> red[2]; unnormalized sel-masked P (bf16 e) -> Pl ---
  {
    float s0[4] = {0.f, 0.f, 0.f, 0.f}, s1[4] = {0.f, 0.f, 0.f, 0.f};
#pragma unroll
    for (int nt = 0; nt < 8; ++nt)
#pragma unroll
      for (int r = 0; r < 4; ++r) {
        if (acc0[nt][r] > c0[r]) s0[r] += acc0[nt][r];
        if (acc1[nt][r] > c1[r]) s1[r] += acc1[nt][r];
      }
#pragma unroll
    for (int r = 0; r < 4; ++r) { s0[r] = qg_sum16(s0[r]); s1[r] = qg_sum16(s1[r]); }
    if (l15 == 0) {
#pragma unroll
      for (int r = 0; r < 4; ++r) {
        red[2][wave][quad * 4 + r]      = s0[r];
        red[2][wave][16 + quad * 4 + r] = s1[r];
      }
    }
  }
#pragma unroll
  for (int nt = 0; nt < 8; ++nt) {
    const int k = wave * 128 + nt * 16 + l15;
#pragma unroll
    for (int r = 0; r < 4; ++r) {
      const int q = quad * 4 + r;
      const float e0 = acc0[nt][r];
      Pl[q][k]      = (e0 > c0[r]) ? __float2bfloat16(e0) : __float2bfloat16(0.f);
      const float e1 = acc1[nt][r];
      Pl[16 + q][k] = (e1 > c1[r]) ? __float2bfloat16(e1) : __float2bfloat16(0.f);
    }
  }
  __syncthreads();   // B3 (covers red[2] and Pl)

  // --- rinv from red[2] ---
  float rinv0[4], rinv1[4];
#pragma unroll
  for (int r = 0; r < 4; ++r) {
    const int q = quad * 4 + r;
    const float Zs0 = ((red[2][0][q] + red[2][1][q]) + (red[2][2][q] + red[2][3][q])) +
                      ((red[2][4][q] + red[2][5][q]) + (red[2][6][q] + red[2][7][q]));
    const float Zs1 = ((red[2][0][16 + q] + red[2][1][16 + q]) + (red[2][2][16 + q] + red[2][3][16 + q])) +
                      ((red[2][4][16 + q] + red[2][5][16 + q]) + (red[2][6][16 + q] + red[2][7][16 + q]));
    rinv0[r] = 1.0f / Zs0;   // row max always selected -> Zs >= 1
    rinv1[r] = 1.0f / Zs1;
  }

  // --- attn stores (final p = e*rinv, identical to v4); drain overlaps PV ---
#pragma unroll
  for (int nt = 0; nt < 8; ++nt) {
    const int k = wave * 128 + nt * 16 + l15;
#pragma unroll
    for (int r = 0; r < 4; ++r) {
      const int q = quad * 4 + r;
      const float e0 = acc0[nt][r];
      attn[abase + (long long)q * SS + k]        = (e0 > c0[r]) ? e0 * rinv0[r] : 0.f;
      const float e1 = acc1[nt][r];
      attn[abase + (long long)(16 + q) * SS + k] = (e1 > c1[r]) ? e1 * rinv1[r] : 0.f;
    }
  }

  // --- Phase 3: PV. wave -> (strip = w&1, d0 = (w>>1)*16), FULL k ---
  const int st = wave & 1;
  const int d0 = (wave >> 1) * 16;
  f32x4 o0 = {}, o1 = {};
  const __hip_bfloat16* pv = vT + vbase + (long long)(d0 + l15) * SS + quad * 8;
  const __hip_bfloat16* pp = &Pl[st * 16 + l15][0] + quad * 8;
#pragma unroll
  for (int ks = 0; ks < 32; ks += 2) {
    bf16x8 a0 = *(const bf16x8*)(pp + ks * 32);
    bf16x8 v0 = *(const bf16x8*)(pv + ks * 32);
    bf16x8 a1 = *(const bf16x8*)(pp + (ks + 1) * 32);
    bf16x8 v1 = *(const bf16x8*)(pv + (ks + 1) * 32);
    __builtin_amdgcn_s_setprio(1);
    o0 = __builtin_amdgcn_mfma_f32_16x16x32_bf16(a0, v0, o0, 0, 0, 0);
    o1 = __builtin_amdgcn_mfma_f32_16x16x32_bf16(a1, v1, o1, 0, 0, 0);
    __builtin_amdgcn_s_setprio(0);
  }
  // post-scale by rinv of this wave's strip; C: row(q)=quad*4+r, col(d)=l15
#pragma unroll
  for (int r = 0; r < 4; ++r) {
    const float rv = st ? rinv1[r] : rinv0[r];
    const float v  = (o0[r] + o1[r]) * rv;
    const int q = q0 + st * 16 + quad * 4 + r;
    ao[((long long)(brow + q)) * EE + h * DD + d0 + l15] = __float2bfloat16(v);
  }
}

// ---------------------------------------------------------------------------
extern "C" void kernel_launch(void* const* d_in, const int* in_sizes, int n_in,
                              void* d_out, int out_size, void* d_ws, size_t ws_size,
                              hipStream_t stream) {
  const float* x     = (const float*)d_in[0];  // [4,1024,1024]
  const float* Wqkv  = (const float*)d_in[1];  // [3072,1024]
  const float* bqkv  = (const float*)d_in[2];  // [3072]
  const float* Wproj = (const float*)d_in[3];  // [1024,1024]
  const float* bproj = (const float*)d_in[4];  // [1024]

  float* out   = (float*)d_out;                        // 4M floats
  float* attnF = out + (size_t)BB * SS * EE;           // 64M floats

  const size_t M1 = 1024 * 1024;
  __hip_bfloat16* w = (__hip_bfloat16*)d_ws;

  if (ws_size >= (size_t)80 * 1024 * 1024) {
    // flat: Wqh 3M, Wql 3M, Wph 1M, qh/ql/kh/kl 4M each, vT 4M, ao 4M = 31M elems = 62MB
    __hip_bfloat16 *Wqh = w, *Wql = Wqh + 3 * M1, *Wph = Wql + 3 * M1;
    __hip_bfloat16 *qh = Wph + M1, *ql = qh + 4 * M1, *kh = ql + 4 * M1, *kl = kh + 4 * M1;
    __hip_bfloat16 *vT = kl + 4 * M1, *ao = vT + 4 * M1;

    split_w<<<4096, 256, 0, stream>>>(Wqkv, Wproj, Wqh, Wql, Wph);
    gemm_qkv<<<dim3(24, 32), 256, 0, stream>>>(
        x, Wqh, Wql, bqkv, qh, ql, kh, kl, vT, 4096);
    fused_attn<<<dim3(BB * HH * 32), 512, 0, stream>>>(
        qh, ql, kh, kl, vT, attnF, ao);
    gemm_out<<<dim3(8, 32), 256, 0, stream>>>(ao, Wph, bproj, out, 4096);
    return;
  }

  // per-batch: 7M shared + 6M per-batch = 13M elems = 26MB
  __hip_bfloat16 *Wqh = w, *Wql = Wqh + 3 * M1, *Wph = Wql + 3 * M1;
  __hip_bfloat16 *qh = Wph + M1, *ql = qh + M1, *kh = ql + M1, *kl = kh + M1;
  __hip_bfloat16 *vT = kl + M1, *ao = vT + M1;

  split_w<<<4096, 256, 0, stream>>>(Wqkv, Wproj, Wqh, Wql, Wph);

  for (int b = 0; b < BB; ++b) {
    const float* xb   = x + (size_t)b * SS * EE;
    float* attnb      = attnF + (size_t)b * HH * SS * SS;
    float* outb       = out + (size_t)b * SS * EE;

    gemm_qkv<<<dim3(24, 8), 256, 0, stream>>>(
        xb, Wqh, Wql, bqkv, qh, ql, kh, kl, vT, 1024);
    fused_attn<<<dim3(HH * 32), 512, 0, stream>>>(
        qh, ql, kh, kl, vT, attnb, ao);
    gemm_out<<<dim3(8, 8), 256, 0, stream>>>(ao, Wph, bproj, outb, 1024);
  }
}